// Round 14
// baseline (239.572 us; speedup 1.0000x reference)
//
#include <hip/hip_runtime.h>
#include <hip/hip_bf16.h>
#include <hip/hip_fp16.h>

// EdgeGAT: 2-layer GAT (heads=4x16 then 1x16) + edge MLP + fc scoring.
// Fixed sizes: N=100000, E=1600000, F_IN=32, EF=8, HID=16.
// Strategy:
//  - CSR by dst via one-pass slack-bucket binning.
//  - Fat kernels: {fine-sort || node1}, {conv1-aggregate || edge-MLP}.
//    The edge-MLP (pure streaming, ~20us of BW work) is co-dispatched with
//    the latency-bound aggregate (53% VALU / 25% HBM) so it runs in the
//    aggregate's idle memory/VALU slack instead of serializing.
//  - conv2's node transform folded into k_agg1's epilogue (round-8 structure;
//    the 3.4M "conflicts" are 2-way events = free per m136 — not the limiter).
//  - ELU via __expf(x)-1; gathered tables h1/h2 fp16; fp32 accumulation.
//  - Skip segment_max (softmax shift-invariant; scores are O(1)).
//  - fc epilogue folded into per-node scalars ps/pd; final kernel is a thin
//    out[e] += ps[src]+pd[dst].

#define FIN 32
#define C1 64   // 4 heads * 16
#define HID 16
#define BSH 8          // 256 nodes per bucket
#define CAP2 6144      // slack bucket capacity (mean 4352, sigma ~64)
#define SOP 68         // padded sO stride (dwords)

__device__ __forceinline__ float leaky02(float x) {
    return x > 0.f ? x : 0.2f * x;
}

// ---------------- init: bucket cursors at slack bases ----------------
__global__ void k_binit3(int* __restrict__ bcur, int nbuck) {
    int b = blockIdx.x * blockDim.x + threadIdx.x;
    if (b < nbuck) bcur[b] = b * CAP2;
}

// ---------------- bucket binning (bin-only) ----------------
__global__ void __launch_bounds__(256) k_bin(
        const int* __restrict__ src, const int* __restrict__ dst,
        int* __restrict__ bcur, unsigned* __restrict__ brec,
        int e, int ep, int nbuck) {
    __shared__ int cnt[512];
    __shared__ int cur[512];
    int tid = threadIdx.x;
    int cb = blockIdx.x * 4096;
    for (int j = tid; j < 512; j += 256) cnt[j] = 0;
    __syncthreads();
    unsigned rec[16];
    int bk[16];
#pragma unroll
    for (int t = 0; t < 16; t++) {
        int i = cb + t * 256 + tid;
        bk[t] = -1;
        if (i < ep) {
            int s, d;
            if (i < e) { s = src[i]; d = dst[i]; }
            else       { s = i - e; d = s; }
            int b = d >> BSH;
            rec[t] = ((unsigned)(d & 255) << 17) | (unsigned)s;
            bk[t] = b;
            atomicAdd(&cnt[b], 1);
        }
    }
    __syncthreads();
    for (int b = tid; b < nbuck; b += 256) {
        int c = cnt[b];
        cur[b] = (c > 0) ? atomicAdd(&bcur[b], c) : 0;
    }
    __syncthreads();
#pragma unroll
    for (int t = 0; t < 16; t++) {
        if (bk[t] >= 0) {
            int p = atomicAdd(&cur[bk[t]], 1);
            if (p < (bk[t] + 1) * CAP2)   // slack-overflow guard
                brec[p] = rec[t];
        }
    }
}

// ---------------- FAT: per-bucket fine sort  ||  node1 ----------------
__global__ void __launch_bounds__(256) k_fineF(
        const unsigned* __restrict__ brec, const int* __restrict__ bcur,
        int* __restrict__ offs, int* __restrict__ oend, int* __restrict__ ssrc,
        const float* __restrict__ x, const float* __restrict__ W1,
        const float* __restrict__ att_s, const float* __restrict__ att_d,
        __half* __restrict__ h1h, float* __restrict__ a1, float* __restrict__ d1,
        int n, int gfine) {
    __shared__ int lcnt[256];
    __shared__ int sbuf[256];
    __shared__ float sW[FIN * C1];     // 8 KB (node1 path)
    __shared__ float sA[C1], sD[C1];
    __shared__ float sX[4 * FIN];
    int tid = threadIdx.x;
    if ((int)blockIdx.x < gfine) {
        int b = blockIdx.x;
        int n0 = b << BSH;
        int base = b * CAP2;
        int cnt = min(bcur[b] - base, CAP2);
        lcnt[tid] = 0;
        __syncthreads();
        for (int i = tid; i < cnt; i += 256) {
            unsigned r = brec[base + i];
            atomicAdd(&lcnt[r >> 17], 1);
        }
        __syncthreads();
        int v = lcnt[tid];
        sbuf[tid] = v;
        __syncthreads();
        for (int off = 1; off < 256; off <<= 1) {
            int u = (tid >= off) ? sbuf[tid - off] : 0;
            __syncthreads();
            sbuf[tid] += u;
            __syncthreads();
        }
        int excl = sbuf[tid] - v;
        if (n0 + tid < n) {
            offs[n0 + tid] = base + excl;
            oend[n0 + tid] = base + excl + v;
        }
        lcnt[tid] = base + excl;    // absolute cursor
        __syncthreads();
        for (int i = tid; i < cnt; i += 256) {
            unsigned r = brec[base + i];
            int p = atomicAdd(&lcnt[r >> 17], 1);
            ssrc[p] = (int)(r & 0x1FFFF);   // 24KB window, L2-absorbed
        }
    } else {
        int nb = (int)blockIdx.x - gfine;   // 4 nodes per block
        for (int i = tid; i < FIN * C1; i += 256) sW[i] = W1[i];
        if (tid < C1) { sA[tid] = att_s[tid]; sD[tid] = att_d[tid]; }
        int bse = nb * 4;
        if (tid < 4 * FIN) {
            int nn = bse + (tid >> 5);
            sX[tid] = (nn < n) ? x[(size_t)nn * FIN + (tid & 31)] : 0.f;
        }
        __syncthreads();
        int li = tid >> 6, c = tid & 63;
        int node = bse + li;
        if (node >= n) return;
        const float* xr = sX + li * FIN;
        float acc = 0.f;
#pragma unroll
        for (int k = 0; k < FIN; k++) acc += xr[k] * sW[k * C1 + c];
        h1h[(size_t)node * C1 + c] = __float2half(acc);
        float pa = acc * sA[c], pb = acc * sD[c];
#pragma unroll
        for (int m = 8; m >= 1; m >>= 1) {
            pa += __shfl_xor(pa, m, 16);
            pb += __shfl_xor(pb, m, 16);
        }
        if ((c & 15) == 0) {
            a1[node * 4 + (c >> 4)] = pa;
            d1[node * 4 + (c >> 4)] = pb;
        }
    }
}

// ---------------- FAT: conv1 aggregate (+folded conv2 transform) || edge MLP
// Aggregate blocks (< gagg): TWO nodes per wave (32-lane halves); 4 groups x
// 8 lanes gather 128B fp16 rows (unroll 8 -> whole chunk's loads in flight).
// Epilogue: butterfly reduce, LDS sO handoff (padded), block-staged sW2
// matvec, h2/a2/d2. MLP blocks (>= gagg): streaming per-edge
// relu(ef@W1+b1)@(W2@fc3)+const -> outp; fills the aggregate's idle BW.
__global__ void __launch_bounds__(256) k_agg1F(
        const __half* __restrict__ h1h, const float* __restrict__ a1,
        const float* __restrict__ d1, const float* __restrict__ b1,
        const float* __restrict__ W2,
        const float* __restrict__ att_s2, const float* __restrict__ att_d2,
        const int* __restrict__ offs, const int* __restrict__ oend,
        const int* __restrict__ ssrc,
        __half* __restrict__ h2h, float* __restrict__ a2, float* __restrict__ d2,
        const float* __restrict__ ea,
        const float* __restrict__ mlpW1, const float* __restrict__ mlpb1,
        const float* __restrict__ mlpW2, const float* __restrict__ mlpb2,
        const float* __restrict__ fcW, const float* __restrict__ fcb,
        float* __restrict__ outp,
        int n, int e, int gagg) {
    __shared__ float4 w4l[4][64];
    __shared__ int    sil[4][64];
    __shared__ float  sO[4][2][SOP];
    __shared__ float  sW2[C1 * HID];   // 4 KB row-major
    __shared__ float  sWm[128];
    __shared__ float  sbm[16];
    __shared__ float  sw2m[17];
    int tid = threadIdx.x;
    if ((int)blockIdx.x >= gagg) {
        // ---------------- edge-MLP branch ----------------
        if (tid < 128) sWm[tid] = mlpW1[tid];
        if (tid < 16)  sbm[tid] = mlpb1[tid];
        if (tid < 16) {
            float s = 0.f;
#pragma unroll
            for (int k = 0; k < 16; k++) s += mlpW2[tid * 16 + k] * fcW[32 + k];
            sw2m[tid] = s;
        } else if (tid == 16) {
            float s = fcb[0];
            for (int k = 0; k < 16; k++) s += mlpb2[k] * fcW[32 + k];
            sw2m[16] = s;
        }
        __syncthreads();
        int eid = ((int)blockIdx.x - gagg) * 256 + tid;
        if (eid >= e) return;
        const float4* ev = (const float4*)ea + (size_t)eid * 4;
        float4 v0 = ev[0], v1 = ev[1], v2 = ev[2], v3 = ev[3];
        float ef[8] = { v0.x * v2.x, v0.y * v2.y, v0.z * v2.z, v0.w * v2.w,
                        v1.x * v3.x, v1.y * v3.y, v1.z * v3.z, v1.w * v3.w };
        float acc = sw2m[16];
#pragma unroll
        for (int j = 0; j < 16; j++) {
            float tt = sbm[j];
#pragma unroll
            for (int i = 0; i < 8; i++) tt += ef[i] * sWm[i * 16 + j];
            acc += fmaxf(tt, 0.f) * sw2m[j];
        }
        outp[eid] = acc;
        return;
    }
    // ---------------- aggregate branch ----------------
    for (int i = tid; i < C1 * HID; i += 256) sW2[i] = W2[i];
    __syncthreads();
    int wid = (int)((blockIdx.x * (size_t)blockDim.x + tid) >> 6);
    int lane = tid & 63;
    int wl = tid >> 6;
    int which = lane >> 5;        // half 0/1
    int lane32 = lane & 31;
    int node = wid * 2 + which;
    if (node >= n) return;
    int sub = lane32 & 7;         // 16B granule within 128B row
    int g   = lane32 >> 3;        // edge group 0..3
    int head = sub >> 1;
    unsigned lane_off = (unsigned)sub * 16u;
    const char* hb = (const char*)h1h;
    float4 dv = ((const float4*)d1)[node];
    int s0 = offs[node], s1v = oend[node];
    float acc[8] = {0.f, 0.f, 0.f, 0.f, 0.f, 0.f, 0.f, 0.f};
    float dsum = 0.f;
    for (int base = s0; base < s1v; base += 32) {
        int cnt = min(32, s1v - base);
        int sl = (lane32 < cnt) ? ssrc[base + lane32] : 0;
        float4 a4 = ((const float4*)a1)[(unsigned)sl];
        float4 w4;
        if (lane32 < cnt) {
            w4.x = __expf(leaky02(a4.x + dv.x));
            w4.y = __expf(leaky02(a4.y + dv.y));
            w4.z = __expf(leaky02(a4.z + dv.z));
            w4.w = __expf(leaky02(a4.w + dv.w));
        } else {
            w4.x = w4.y = w4.z = w4.w = 0.f;
        }
        w4l[wl][lane] = w4;
        sil[wl][lane] = sl << 7;           // pre-shifted byte offset
        __builtin_amdgcn_wave_barrier();
        int cnt4 = (cnt + 3) & ~3;
        int lbase = which << 5;
#pragma unroll 8
        for (int j = g; j < cnt4; j += 4) {
            int soff = sil[wl][lbase + j];
            float w = ((const float*)&w4l[wl][lbase + j])[head];
            float4 raw = *(const float4*)(hb + (unsigned)soff + lane_off);
            float2 f0 = __half22float2(*(__half2*)&raw.x);
            float2 f1 = __half22float2(*(__half2*)&raw.y);
            float2 f2 = __half22float2(*(__half2*)&raw.z);
            float2 f3 = __half22float2(*(__half2*)&raw.w);
            acc[0] = fmaf(w, f0.x, acc[0]);
            acc[1] = fmaf(w, f0.y, acc[1]);
            acc[2] = fmaf(w, f1.x, acc[2]);
            acc[3] = fmaf(w, f1.y, acc[3]);
            acc[4] = fmaf(w, f2.x, acc[4]);
            acc[5] = fmaf(w, f2.y, acc[5]);
            acc[6] = fmaf(w, f3.x, acc[6]);
            acc[7] = fmaf(w, f3.y, acc[7]);
            dsum += w;
        }
        __builtin_amdgcn_wave_barrier();
    }
    // butterfly reduce across the 4 edge groups (lane bits 3,4)
#pragma unroll
    for (int m = 8; m <= 16; m <<= 1) {
#pragma unroll
        for (int i = 0; i < 8; i++) acc[i] += __shfl_xor(acc[i], m, 64);
        dsum += __shfl_xor(dsum, m, 64);
    }
    if (lane32 < 8) {    // sub-lane owns 8 channels: bias + ELU, stage to sO
        float inv = 1.f / (dsum + 1e-16f);
        float4 bA = ((const float4*)b1)[lane32 * 2];
        float4 bB = ((const float4*)b1)[lane32 * 2 + 1];
        float4 oA, oB;
        oA.x = acc[0] * inv + bA.x;
        oA.y = acc[1] * inv + bA.y;
        oA.z = acc[2] * inv + bA.z;
        oA.w = acc[3] * inv + bA.w;
        oB.x = acc[4] * inv + bB.x;
        oB.y = acc[5] * inv + bB.y;
        oB.z = acc[6] * inv + bB.z;
        oB.w = acc[7] * inv + bB.w;
        oA.x = oA.x > 0.f ? oA.x : (__expf(oA.x) - 1.f);
        oA.y = oA.y > 0.f ? oA.y : (__expf(oA.y) - 1.f);
        oA.z = oA.z > 0.f ? oA.z : (__expf(oA.z) - 1.f);
        oA.w = oA.w > 0.f ? oA.w : (__expf(oA.w) - 1.f);
        oB.x = oB.x > 0.f ? oB.x : (__expf(oB.x) - 1.f);
        oB.y = oB.y > 0.f ? oB.y : (__expf(oB.y) - 1.f);
        oB.z = oB.z > 0.f ? oB.z : (__expf(oB.z) - 1.f);
        oB.w = oB.w > 0.f ? oB.w : (__expf(oB.w) - 1.f);
        *((float4*)&sO[wl][which][lane32 * 8])     = oA;
        *((float4*)&sO[wl][which][lane32 * 8 + 4]) = oB;
    }
    __builtin_amdgcn_wave_barrier();
    // folded conv2 node transform: h2[c] = sum_k out1[k]*W2[k][c]
    int c = lane32 & 15, kh = lane32 >> 4;
    const float* orow = sO[wl][which];
    float part = 0.f;
#pragma unroll
    for (int k = 0; k < 32; k++)
        part += orow[kh * 32 + k] * sW2[(kh * 32 + k) * HID + c];
    part += __shfl_xor(part, 16, 64);          // combine k-halves
    if (lane32 < 16) h2h[(size_t)node * HID + c] = __float2half(part);
    float pa = part * att_s2[c], pb = part * att_d2[c];
#pragma unroll
    for (int m = 8; m >= 1; m >>= 1) {
        pa += __shfl_xor(pa, m, 64);
        pb += __shfl_xor(pb, m, 64);
    }
    if (lane32 == 0) { a2[node] = pa; d2[node] = pb; }
}

// ---------------- conv2 aggregate + bias + fold fc -> ps/pd ----------------
__global__ void __launch_bounds__(256) k_agg2(
        const __half* __restrict__ h2h, const float* __restrict__ a2,
        const float* __restrict__ d2, const float* __restrict__ b2,
        const float* __restrict__ fcW,
        const int* __restrict__ offs, const int* __restrict__ oend,
        const int* __restrict__ ssrc,
        float* __restrict__ ps, float* __restrict__ pd, int n) {
    __shared__ float2 wsl[4][64];
    int wid = (int)((blockIdx.x * (size_t)blockDim.x + threadIdx.x) >> 6);
    int lane = threadIdx.x & 63;
    int wl = threadIdx.x >> 6;
    int which = lane >> 5;
    int lane32 = lane & 31;
    int node = wid * 2 + which;
    if (node >= n) return;
    int sub = lane32 & 1;
    int g   = lane32 >> 1;
    unsigned lane_off = (unsigned)sub * 16u;
    const char* hb = (const char*)h2h;
    float dvv = d2[node];
    int s0 = offs[node], s1v = oend[node];
    float acc[8] = {0.f, 0.f, 0.f, 0.f, 0.f, 0.f, 0.f, 0.f};
    float dsum = 0.f;
    for (int base = s0; base < s1v; base += 32) {
        int cnt = min(32, s1v - base);
        int sl = (lane32 < cnt) ? ssrc[base + lane32] : 0;
        float av = a2[(unsigned)sl];
        float w = (lane32 < cnt) ? __expf(leaky02(av + dvv)) : 0.f;
        wsl[wl][lane] = make_float2(w, __int_as_float(sl << 5));  // pre-shifted
        __builtin_amdgcn_wave_barrier();
        int cnt16 = (cnt + 15) & ~15;
        int lbase = which << 5;
#pragma unroll 2
        for (int j = g; j < cnt16; j += 16) {
            float2 e0 = wsl[wl][lbase + j];
            unsigned soff = (unsigned)__float_as_int(e0.y);
            float4 raw = *(const float4*)(hb + soff + lane_off);
            float2 f0 = __half22float2(*(__half2*)&raw.x);
            float2 f1 = __half22float2(*(__half2*)&raw.y);
            float2 f2 = __half22float2(*(__half2*)&raw.z);
            float2 f3 = __half22float2(*(__half2*)&raw.w);
            acc[0] = fmaf(e0.x, f0.x, acc[0]);
            acc[1] = fmaf(e0.x, f0.y, acc[1]);
            acc[2] = fmaf(e0.x, f1.x, acc[2]);
            acc[3] = fmaf(e0.x, f1.y, acc[3]);
            acc[4] = fmaf(e0.x, f2.x, acc[4]);
            acc[5] = fmaf(e0.x, f2.y, acc[5]);
            acc[6] = fmaf(e0.x, f3.x, acc[6]);
            acc[7] = fmaf(e0.x, f3.y, acc[7]);
            dsum += e0.x;
        }
        __builtin_amdgcn_wave_barrier();
    }
#pragma unroll
    for (int m = 2; m <= 16; m <<= 1) {
#pragma unroll
        for (int i = 0; i < 8; i++) acc[i] += __shfl_xor(acc[i], m, 64);
        dsum += __shfl_xor(dsum, m, 64);
    }
    float p1 = 0.f, p2 = 0.f;
    if (lane32 < 2) {
        float inv = 1.f / (dsum + 1e-16f);
        float4 bA = ((const float4*)b2)[lane32 * 2];
        float4 bB = ((const float4*)b2)[lane32 * 2 + 1];
        float4 fsA = ((const float4*)fcW)[lane32 * 2];
        float4 fsB = ((const float4*)fcW)[lane32 * 2 + 1];
        float4 fdA = ((const float4*)fcW)[4 + lane32 * 2];
        float4 fdB = ((const float4*)fcW)[4 + lane32 * 2 + 1];
        float h0 = acc[0] * inv + bA.x, h1v = acc[1] * inv + bA.y;
        float h2v = acc[2] * inv + bA.z, h3 = acc[3] * inv + bA.w;
        float h4 = acc[4] * inv + bB.x, h5 = acc[5] * inv + bB.y;
        float h6 = acc[6] * inv + bB.z, h7 = acc[7] * inv + bB.w;
        p1 = h0 * fsA.x + h1v * fsA.y + h2v * fsA.z + h3 * fsA.w
           + h4 * fsB.x + h5 * fsB.y + h6 * fsB.z + h7 * fsB.w;
        p2 = h0 * fdA.x + h1v * fdA.y + h2v * fdA.z + h3 * fdA.w
           + h4 * fdB.x + h5 * fdB.y + h6 * fdB.z + h7 * fdB.w;
    }
    p1 += __shfl_xor(p1, 1, 64);
    p2 += __shfl_xor(p2, 1, 64);
    if (lane32 == 0) { ps[node] = p1; pd[node] = p2; }
}

// ---------------- final: add per-node scalars to edge-MLP partial ----------
__global__ void __launch_bounds__(256) k_final2(
        const int* __restrict__ src, const int* __restrict__ dst,
        const float* __restrict__ ps, const float* __restrict__ pd,
        float* __restrict__ out, int e) {
    int eid = blockIdx.x * blockDim.x + threadIdx.x;
    if (eid < e) out[eid] += ps[src[eid]] + pd[dst[eid]];
}

extern "C" void kernel_launch(void* const* d_in, const int* in_sizes, int n_in,
                              void* d_out, int out_size, void* d_ws, size_t ws_size,
                              hipStream_t stream) {
    const float* x        = (const float*)d_in[0];
    const int*   eidx     = (const int*)d_in[1];
    const float* eattr    = (const float*)d_in[2];
    const float* W1       = (const float*)d_in[5];
    const float* att_s1   = (const float*)d_in[6];
    const float* att_d1   = (const float*)d_in[7];
    const float* b1       = (const float*)d_in[8];
    const float* W2       = (const float*)d_in[9];
    const float* att_s2   = (const float*)d_in[10];
    const float* att_d2   = (const float*)d_in[11];
    const float* b2       = (const float*)d_in[12];
    const float* mlp_W1   = (const float*)d_in[13];
    const float* mlp_b1   = (const float*)d_in[14];
    const float* mlp_W2   = (const float*)d_in[15];
    const float* mlp_b2   = (const float*)d_in[16];
    const float* fc_W     = (const float*)d_in[17];
    const float* fc_b     = (const float*)d_in[18];

    const int n = in_sizes[0] / FIN;          // 100000
    const int e = in_sizes[2] / 16;           // 1600000
    const int ep = e + n;                     // with self loops
    const int* src = eidx;
    const int* dst = eidx + e;
    const int nbuck = (n + 255) >> BSH;       // 391 (<= 512)

    // workspace layout (byte-carved, 256B-aligned blocks)
    char* p = (char*)d_ws;
    auto carve = [&](size_t bytes) {
        char* r = p;
        p += (bytes + 255) & ~(size_t)255;
        return r;
    };
    __half* h1h  = (__half*)carve((size_t)n * C1 * 2);
    __half* h2h  = (__half*)carve((size_t)n * HID * 2);
    float*  a1   = (float*)carve((size_t)n * 4 * 4);
    float*  d1   = (float*)carve((size_t)n * 4 * 4);
    float*  a2   = (float*)carve((size_t)n * 4);
    float*  d2   = (float*)carve((size_t)n * 4);
    float*  ps   = (float*)carve((size_t)n * 4);
    float*  pd   = (float*)carve((size_t)n * 4);
    int*    offs = (int*)carve((size_t)n * 4);
    int*    oendp= (int*)carve((size_t)n * 4);
    int*    bcur = (int*)carve(512 * 4);
    int*    ssrc = (int*)carve((size_t)nbuck * CAP2 * 4);
    unsigned* brec = (unsigned*)carve((size_t)nbuck * CAP2 * 4);

    float* outp = (float*)d_out;

    const int gbin  = (ep + 4095) / 4096;     // 416
    const int gmlp  = (e + 255) / 256;        // 6250
    const int gnode1 = (n + 3) / 4;           // 25000
    const int npair = (n + 1) / 2;            // 50000 waves
    const int gagg  = (npair * 64 + 255) / 256;  // 12500

    // 1) init cursors
    k_binit3<<<2, 256, 0, stream>>>(bcur, nbuck);
    // 2) bucket binning
    k_bin<<<gbin, 256, 0, stream>>>(src, dst, bcur, brec, e, ep, nbuck);
    // 3) FAT: fine sort || node1
    k_fineF<<<nbuck + gnode1, 256, 0, stream>>>(brec, bcur, offs, oendp, ssrc,
                                                x, W1, att_s1, att_d1,
                                                h1h, a1, d1, n, nbuck);
    // 4) FAT: conv1 aggregate (+folded conv2 transform) || edge MLP
    k_agg1F<<<gagg + gmlp, 256, 0, stream>>>(
        h1h, a1, d1, b1, W2, att_s2, att_d2, offs, oendp, ssrc, h2h, a2, d2,
        eattr, mlp_W1, mlp_b1, mlp_W2, mlp_b2, fc_W, fc_b, outp, n, e, gagg);
    // 5) conv2 aggregate -> ps/pd
    k_agg2<<<(npair * 64 + 255) / 256, 256, 0, stream>>>(
        h2h, a2, d2, b2, fc_W, offs, oendp, ssrc, ps, pd, n);
    // 6) final add
    k_final2<<<(e + 255) / 256, 256, 0, stream>>>(src, dst, ps, pd, outp, e);
}

// Round 15
// 186.110 us; speedup vs baseline: 1.2873x; 1.2873x over previous
//
#include <hip/hip_runtime.h>
#include <hip/hip_bf16.h>
#include <hip/hip_fp16.h>

// EdgeGAT: 2-layer GAT (heads=4x16 then 1x16) + edge MLP + fc scoring.
// Fixed sizes: N=100000, E=1600000, F_IN=32, EF=8, HID=16.
// Strategy:
//  - CSR by dst via one-pass slack-bucket binning.
//  - Fat kernels: {bin || edge-MLP}, {fine-sort || node1}. (Round 14 showed
//    fusing MLP into the gather kernel collapses occupancy via branch-union
//    VGPR allocation — keep high-pressure branches in separate kernels.)
//  - conv2's node transform folded into k_agg1's epilogue (round-8 LDS
//    structure; 3.4M 2-way LDS events are free per m136).
//  - Gather inner loops written as fmaf(__half2float(h), w, acc) so clang
//    emits v_fma_mix_f32 (fp16 operand in fp32 FMA): cuts the cvt chain,
//    ~33% fewer inner-loop VALU ops, identical numerics.
//  - ELU via __expf(x)-1; h1/h2 fp16; fp32 accumulation everywhere.
//  - Skip segment_max (softmax shift-invariant; scores are O(1)).
//  - fc epilogue folded into per-node ps/pd; final kernel is a thin
//    out[e] += ps[src]+pd[dst].

#define FIN 32
#define C1 64   // 4 heads * 16
#define HID 16
#define BSH 8          // 256 nodes per bucket
#define CAP2 6144      // slack bucket capacity (mean 4352, sigma ~64)
#define SOP 68         // padded sO stride (dwords)

__device__ __forceinline__ float leaky02(float x) {
    return x > 0.f ? x : 0.2f * x;
}

// ---------------- init: bucket cursors at slack bases ----------------
__global__ void k_binit3(int* __restrict__ bcur, int nbuck) {
    int b = blockIdx.x * blockDim.x + threadIdx.x;
    if (b < nbuck) bcur[b] = b * CAP2;
}

// ---------------- FAT 1: bucket binning  ||  edge MLP ----------------
__global__ void __launch_bounds__(256) k_binF(
        const int* __restrict__ src, const int* __restrict__ dst,
        int* __restrict__ bcur, unsigned* __restrict__ brec,
        const float* __restrict__ ea,
        const float* __restrict__ mlpW1, const float* __restrict__ mlpb1,
        const float* __restrict__ mlpW2, const float* __restrict__ mlpb2,
        const float* __restrict__ fcW, const float* __restrict__ fcb,
        float* __restrict__ outp,
        int e, int ep, int nbuck, int gbin) {
    __shared__ int cnt[512];
    __shared__ int cur[512];
    __shared__ float sW[128];
    __shared__ float sb[16];
    __shared__ float sw2[17];
    int tid = threadIdx.x;
    if ((int)blockIdx.x < gbin) {
        int cb = blockIdx.x * 4096;
        for (int j = tid; j < 512; j += 256) cnt[j] = 0;
        __syncthreads();
        unsigned rec[16];
        int bk[16];
#pragma unroll
        for (int t = 0; t < 16; t++) {
            int i = cb + t * 256 + tid;
            bk[t] = -1;
            if (i < ep) {
                int s, d;
                if (i < e) { s = src[i]; d = dst[i]; }
                else       { s = i - e; d = s; }
                int b = d >> BSH;
                rec[t] = ((unsigned)(d & 255) << 17) | (unsigned)s;
                bk[t] = b;
                atomicAdd(&cnt[b], 1);
            }
        }
        __syncthreads();
        for (int b = tid; b < nbuck; b += 256) {
            int c = cnt[b];
            cur[b] = (c > 0) ? atomicAdd(&bcur[b], c) : 0;
        }
        __syncthreads();
#pragma unroll
        for (int t = 0; t < 16; t++) {
            if (bk[t] >= 0) {
                int p = atomicAdd(&cur[bk[t]], 1);
                if (p < (bk[t] + 1) * CAP2)   // slack-overflow guard
                    brec[p] = rec[t];
            }
        }
    } else {
        if (tid < 128) sW[tid] = mlpW1[tid];
        if (tid < 16)  sb[tid] = mlpb1[tid];
        if (tid < 16) {
            float s = 0.f;
#pragma unroll
            for (int k = 0; k < 16; k++) s += mlpW2[tid * 16 + k] * fcW[32 + k];
            sw2[tid] = s;
        } else if (tid == 16) {
            float s = fcb[0];
            for (int k = 0; k < 16; k++) s += mlpb2[k] * fcW[32 + k];
            sw2[16] = s;
        }
        __syncthreads();
        int eid = ((int)blockIdx.x - gbin) * 256 + tid;
        if (eid >= e) return;
        const float4* ev = (const float4*)ea + (size_t)eid * 4;
        float4 v0 = ev[0], v1 = ev[1], v2 = ev[2], v3 = ev[3];
        float ef[8] = { v0.x * v2.x, v0.y * v2.y, v0.z * v2.z, v0.w * v2.w,
                        v1.x * v3.x, v1.y * v3.y, v1.z * v3.z, v1.w * v3.w };
        float acc = sw2[16];
#pragma unroll
        for (int j = 0; j < 16; j++) {
            float tt = sb[j];
#pragma unroll
            for (int i = 0; i < 8; i++) tt += ef[i] * sW[i * 16 + j];
            acc += fmaxf(tt, 0.f) * sw2[j];
        }
        outp[eid] = acc;
    }
}

// ---------------- FAT 2: per-bucket fine sort  ||  node1 ----------------
__global__ void __launch_bounds__(256) k_fineF(
        const unsigned* __restrict__ brec, const int* __restrict__ bcur,
        int* __restrict__ offs, int* __restrict__ oend, int* __restrict__ ssrc,
        const float* __restrict__ x, const float* __restrict__ W1,
        const float* __restrict__ att_s, const float* __restrict__ att_d,
        __half* __restrict__ h1h, float* __restrict__ a1, float* __restrict__ d1,
        int n, int gfine) {
    __shared__ int lcnt[256];
    __shared__ int sbuf[256];
    __shared__ float sW[FIN * C1];     // 8 KB (node1 path)
    __shared__ float sA[C1], sD[C1];
    __shared__ float sX[4 * FIN];
    int tid = threadIdx.x;
    if ((int)blockIdx.x < gfine) {
        int b = blockIdx.x;
        int n0 = b << BSH;
        int base = b * CAP2;
        int cnt = min(bcur[b] - base, CAP2);
        lcnt[tid] = 0;
        __syncthreads();
        for (int i = tid; i < cnt; i += 256) {
            unsigned r = brec[base + i];
            atomicAdd(&lcnt[r >> 17], 1);
        }
        __syncthreads();
        int v = lcnt[tid];
        sbuf[tid] = v;
        __syncthreads();
        for (int off = 1; off < 256; off <<= 1) {
            int u = (tid >= off) ? sbuf[tid - off] : 0;
            __syncthreads();
            sbuf[tid] += u;
            __syncthreads();
        }
        int excl = sbuf[tid] - v;
        if (n0 + tid < n) {
            offs[n0 + tid] = base + excl;
            oend[n0 + tid] = base + excl + v;
        }
        lcnt[tid] = base + excl;    // absolute cursor
        __syncthreads();
        for (int i = tid; i < cnt; i += 256) {
            unsigned r = brec[base + i];
            int p = atomicAdd(&lcnt[r >> 17], 1);
            ssrc[p] = (int)(r & 0x1FFFF);   // 24KB window, L2-absorbed
        }
    } else {
        int nb = (int)blockIdx.x - gfine;   // 4 nodes per block
        for (int i = tid; i < FIN * C1; i += 256) sW[i] = W1[i];
        if (tid < C1) { sA[tid] = att_s[tid]; sD[tid] = att_d[tid]; }
        int bse = nb * 4;
        if (tid < 4 * FIN) {
            int nn = bse + (tid >> 5);
            sX[tid] = (nn < n) ? x[(size_t)nn * FIN + (tid & 31)] : 0.f;
        }
        __syncthreads();
        int li = tid >> 6, c = tid & 63;
        int node = bse + li;
        if (node >= n) return;
        const float* xr = sX + li * FIN;
        float acc = 0.f;
#pragma unroll
        for (int k = 0; k < FIN; k++) acc += xr[k] * sW[k * C1 + c];
        h1h[(size_t)node * C1 + c] = __float2half(acc);
        float pa = acc * sA[c], pb = acc * sD[c];
#pragma unroll
        for (int m = 8; m >= 1; m >>= 1) {
            pa += __shfl_xor(pa, m, 16);
            pb += __shfl_xor(pb, m, 16);
        }
        if ((c & 15) == 0) {
            a1[node * 4 + (c >> 4)] = pa;
            d1[node * 4 + (c >> 4)] = pb;
        }
    }
}

// ---------------- conv1 aggregate + ELU + folded conv2 node transform -----
// TWO nodes per wave (32-lane halves); 4 groups x 8 lanes gather 128B fp16
// rows (unroll 4, fma_mix inner). Epilogue: butterfly reduce, padded sO
// handoff, block-staged sW2 matvec, h2/a2/d2.
__global__ void __launch_bounds__(256) k_agg1F(
        const __half* __restrict__ h1h, const float* __restrict__ a1,
        const float* __restrict__ d1, const float* __restrict__ b1,
        const float* __restrict__ W2,
        const float* __restrict__ att_s2, const float* __restrict__ att_d2,
        const int* __restrict__ offs, const int* __restrict__ oend,
        const int* __restrict__ ssrc,
        __half* __restrict__ h2h, float* __restrict__ a2, float* __restrict__ d2,
        int n) {
    __shared__ float4 w4l[4][64];
    __shared__ int    sil[4][64];
    __shared__ float  sO[4][2][SOP];
    __shared__ float  sW2[C1 * HID];   // 4 KB row-major
    int tid = threadIdx.x;
    for (int i = tid; i < C1 * HID; i += 256) sW2[i] = W2[i];
    __syncthreads();
    int wid = (int)((blockIdx.x * (size_t)blockDim.x + tid) >> 6);
    int lane = tid & 63;
    int wl = tid >> 6;
    int which = lane >> 5;        // half 0/1
    int lane32 = lane & 31;
    int node = wid * 2 + which;
    if (node >= n) return;
    int sub = lane32 & 7;         // 16B granule within 128B row
    int g   = lane32 >> 3;        // edge group 0..3
    int head = sub >> 1;
    unsigned lane_off = (unsigned)sub * 16u;
    const char* hb = (const char*)h1h;
    float4 dv = ((const float4*)d1)[node];
    int s0 = offs[node], s1v = oend[node];
    float acc[8] = {0.f, 0.f, 0.f, 0.f, 0.f, 0.f, 0.f, 0.f};
    float dsum = 0.f;
    for (int base = s0; base < s1v; base += 32) {
        int cnt = min(32, s1v - base);
        int sl = (lane32 < cnt) ? ssrc[base + lane32] : 0;
        float4 a4 = ((const float4*)a1)[(unsigned)sl];
        float4 w4;
        if (lane32 < cnt) {
            w4.x = __expf(leaky02(a4.x + dv.x));
            w4.y = __expf(leaky02(a4.y + dv.y));
            w4.z = __expf(leaky02(a4.z + dv.z));
            w4.w = __expf(leaky02(a4.w + dv.w));
        } else {
            w4.x = w4.y = w4.z = w4.w = 0.f;
        }
        w4l[wl][lane] = w4;
        sil[wl][lane] = sl << 7;           // pre-shifted byte offset
        __builtin_amdgcn_wave_barrier();
        int cnt4 = (cnt + 3) & ~3;
        int lbase = which << 5;
#pragma unroll 4
        for (int j = g; j < cnt4; j += 4) {
            int soff = sil[wl][lbase + j];
            float w = ((const float*)&w4l[wl][lbase + j])[head];
            float4 raw = *(const float4*)(hb + (unsigned)soff + lane_off);
            const __half* hr = (const __half*)&raw;
            // fmaf(half2float(h), w, acc) -> v_fma_mix_f32 (no cvt chain)
            acc[0] = fmaf(__half2float(hr[0]), w, acc[0]);
            acc[1] = fmaf(__half2float(hr[1]), w, acc[1]);
            acc[2] = fmaf(__half2float(hr[2]), w, acc[2]);
            acc[3] = fmaf(__half2float(hr[3]), w, acc[3]);
            acc[4] = fmaf(__half2float(hr[4]), w, acc[4]);
            acc[5] = fmaf(__half2float(hr[5]), w, acc[5]);
            acc[6] = fmaf(__half2float(hr[6]), w, acc[6]);
            acc[7] = fmaf(__half2float(hr[7]), w, acc[7]);
            dsum += w;
        }
        __builtin_amdgcn_wave_barrier();
    }
    // butterfly reduce across the 4 edge groups (lane bits 3,4)
#pragma unroll
    for (int m = 8; m <= 16; m <<= 1) {
#pragma unroll
        for (int i = 0; i < 8; i++) acc[i] += __shfl_xor(acc[i], m, 64);
        dsum += __shfl_xor(dsum, m, 64);
    }
    if (lane32 < 8) {    // sub-lane owns 8 channels: bias + ELU, stage to sO
        float inv = 1.f / (dsum + 1e-16f);
        float4 bA = ((const float4*)b1)[lane32 * 2];
        float4 bB = ((const float4*)b1)[lane32 * 2 + 1];
        float4 oA, oB;
        oA.x = acc[0] * inv + bA.x;
        oA.y = acc[1] * inv + bA.y;
        oA.z = acc[2] * inv + bA.z;
        oA.w = acc[3] * inv + bA.w;
        oB.x = acc[4] * inv + bB.x;
        oB.y = acc[5] * inv + bB.y;
        oB.z = acc[6] * inv + bB.z;
        oB.w = acc[7] * inv + bB.w;
        oA.x = oA.x > 0.f ? oA.x : (__expf(oA.x) - 1.f);
        oA.y = oA.y > 0.f ? oA.y : (__expf(oA.y) - 1.f);
        oA.z = oA.z > 0.f ? oA.z : (__expf(oA.z) - 1.f);
        oA.w = oA.w > 0.f ? oA.w : (__expf(oA.w) - 1.f);
        oB.x = oB.x > 0.f ? oB.x : (__expf(oB.x) - 1.f);
        oB.y = oB.y > 0.f ? oB.y : (__expf(oB.y) - 1.f);
        oB.z = oB.z > 0.f ? oB.z : (__expf(oB.z) - 1.f);
        oB.w = oB.w > 0.f ? oB.w : (__expf(oB.w) - 1.f);
        *((float4*)&sO[wl][which][lane32 * 8])     = oA;
        *((float4*)&sO[wl][which][lane32 * 8 + 4]) = oB;
    }
    __builtin_amdgcn_wave_barrier();
    // folded conv2 node transform: h2[c] = sum_k out1[k]*W2[k][c]
    int c = lane32 & 15, kh = lane32 >> 4;
    const float* orow = sO[wl][which];
    float part = 0.f;
#pragma unroll
    for (int k = 0; k < 32; k++)
        part += orow[kh * 32 + k] * sW2[(kh * 32 + k) * HID + c];
    part += __shfl_xor(part, 16, 64);          // combine k-halves
    if (lane32 < 16) h2h[(size_t)node * HID + c] = __float2half(part);
    float pa = part * att_s2[c], pb = part * att_d2[c];
#pragma unroll
    for (int m = 8; m >= 1; m >>= 1) {
        pa += __shfl_xor(pa, m, 64);
        pb += __shfl_xor(pb, m, 64);
    }
    if (lane32 == 0) { a2[node] = pa; d2[node] = pb; }
}

// ---------------- conv2 aggregate + bias + fold fc -> ps/pd ----------------
// TWO nodes per wave; per half: 16 groups x 2 lanes gather 32B fp16 rows.
__global__ void __launch_bounds__(256) k_agg2(
        const __half* __restrict__ h2h, const float* __restrict__ a2,
        const float* __restrict__ d2, const float* __restrict__ b2,
        const float* __restrict__ fcW,
        const int* __restrict__ offs, const int* __restrict__ oend,
        const int* __restrict__ ssrc,
        float* __restrict__ ps, float* __restrict__ pd, int n) {
    __shared__ float2 wsl[4][64];
    int wid = (int)((blockIdx.x * (size_t)blockDim.x + threadIdx.x) >> 6);
    int lane = threadIdx.x & 63;
    int wl = threadIdx.x >> 6;
    int which = lane >> 5;
    int lane32 = lane & 31;
    int node = wid * 2 + which;
    if (node >= n) return;
    int sub = lane32 & 1;
    int g   = lane32 >> 1;
    unsigned lane_off = (unsigned)sub * 16u;
    const char* hb = (const char*)h2h;
    float dvv = d2[node];
    int s0 = offs[node], s1v = oend[node];
    float acc[8] = {0.f, 0.f, 0.f, 0.f, 0.f, 0.f, 0.f, 0.f};
    float dsum = 0.f;
    for (int base = s0; base < s1v; base += 32) {
        int cnt = min(32, s1v - base);
        int sl = (lane32 < cnt) ? ssrc[base + lane32] : 0;
        float av = a2[(unsigned)sl];
        float w = (lane32 < cnt) ? __expf(leaky02(av + dvv)) : 0.f;
        wsl[wl][lane] = make_float2(w, __int_as_float(sl << 5));  // pre-shifted
        __builtin_amdgcn_wave_barrier();
        int cnt16 = (cnt + 15) & ~15;
        int lbase = which << 5;
#pragma unroll 2
        for (int j = g; j < cnt16; j += 16) {
            float2 e0 = wsl[wl][lbase + j];
            unsigned soff = (unsigned)__float_as_int(e0.y);
            float4 raw = *(const float4*)(hb + soff + lane_off);
            const __half* hr = (const __half*)&raw;
            acc[0] = fmaf(__half2float(hr[0]), e0.x, acc[0]);
            acc[1] = fmaf(__half2float(hr[1]), e0.x, acc[1]);
            acc[2] = fmaf(__half2float(hr[2]), e0.x, acc[2]);
            acc[3] = fmaf(__half2float(hr[3]), e0.x, acc[3]);
            acc[4] = fmaf(__half2float(hr[4]), e0.x, acc[4]);
            acc[5] = fmaf(__half2float(hr[5]), e0.x, acc[5]);
            acc[6] = fmaf(__half2float(hr[6]), e0.x, acc[6]);
            acc[7] = fmaf(__half2float(hr[7]), e0.x, acc[7]);
            dsum += e0.x;
        }
        __builtin_amdgcn_wave_barrier();
    }
#pragma unroll
    for (int m = 2; m <= 16; m <<= 1) {
#pragma unroll
        for (int i = 0; i < 8; i++) acc[i] += __shfl_xor(acc[i], m, 64);
        dsum += __shfl_xor(dsum, m, 64);
    }
    float p1 = 0.f, p2 = 0.f;
    if (lane32 < 2) {
        float inv = 1.f / (dsum + 1e-16f);
        float4 bA = ((const float4*)b2)[lane32 * 2];
        float4 bB = ((const float4*)b2)[lane32 * 2 + 1];
        float4 fsA = ((const float4*)fcW)[lane32 * 2];
        float4 fsB = ((const float4*)fcW)[lane32 * 2 + 1];
        float4 fdA = ((const float4*)fcW)[4 + lane32 * 2];
        float4 fdB = ((const float4*)fcW)[4 + lane32 * 2 + 1];
        float h0 = acc[0] * inv + bA.x, h1v = acc[1] * inv + bA.y;
        float h2v = acc[2] * inv + bA.z, h3 = acc[3] * inv + bA.w;
        float h4 = acc[4] * inv + bB.x, h5 = acc[5] * inv + bB.y;
        float h6 = acc[6] * inv + bB.z, h7 = acc[7] * inv + bB.w;
        p1 = h0 * fsA.x + h1v * fsA.y + h2v * fsA.z + h3 * fsA.w
           + h4 * fsB.x + h5 * fsB.y + h6 * fsB.z + h7 * fsB.w;
        p2 = h0 * fdA.x + h1v * fdA.y + h2v * fdA.z + h3 * fdA.w
           + h4 * fdB.x + h5 * fdB.y + h6 * fdB.z + h7 * fdB.w;
    }
    p1 += __shfl_xor(p1, 1, 64);
    p2 += __shfl_xor(p2, 1, 64);
    if (lane32 == 0) { ps[node] = p1; pd[node] = p2; }
}

// ---------------- final: add per-node scalars to edge-MLP partial ----------
__global__ void __launch_bounds__(256) k_final2(
        const int* __restrict__ src, const int* __restrict__ dst,
        const float* __restrict__ ps, const float* __restrict__ pd,
        float* __restrict__ out, int e) {
    int eid = blockIdx.x * blockDim.x + threadIdx.x;
    if (eid < e) out[eid] += ps[src[eid]] + pd[dst[eid]];
}

extern "C" void kernel_launch(void* const* d_in, const int* in_sizes, int n_in,
                              void* d_out, int out_size, void* d_ws, size_t ws_size,
                              hipStream_t stream) {
    const float* x        = (const float*)d_in[0];
    const int*   eidx     = (const int*)d_in[1];
    const float* eattr    = (const float*)d_in[2];
    const float* W1       = (const float*)d_in[5];
    const float* att_s1   = (const float*)d_in[6];
    const float* att_d1   = (const float*)d_in[7];
    const float* b1       = (const float*)d_in[8];
    const float* W2       = (const float*)d_in[9];
    const float* att_s2   = (const float*)d_in[10];
    const float* att_d2   = (const float*)d_in[11];
    const float* b2       = (const float*)d_in[12];
    const float* mlp_W1   = (const float*)d_in[13];
    const float* mlp_b1   = (const float*)d_in[14];
    const float* mlp_W2   = (const float*)d_in[15];
    const float* mlp_b2   = (const float*)d_in[16];
    const float* fc_W     = (const float*)d_in[17];
    const float* fc_b     = (const float*)d_in[18];

    const int n = in_sizes[0] / FIN;          // 100000
    const int e = in_sizes[2] / 16;           // 1600000
    const int ep = e + n;                     // with self loops
    const int* src = eidx;
    const int* dst = eidx + e;
    const int nbuck = (n + 255) >> BSH;       // 391 (<= 512)

    // workspace layout (byte-carved, 256B-aligned blocks)
    char* p = (char*)d_ws;
    auto carve = [&](size_t bytes) {
        char* r = p;
        p += (bytes + 255) & ~(size_t)255;
        return r;
    };
    __half* h1h  = (__half*)carve((size_t)n * C1 * 2);
    __half* h2h  = (__half*)carve((size_t)n * HID * 2);
    float*  a1   = (float*)carve((size_t)n * 4 * 4);
    float*  d1   = (float*)carve((size_t)n * 4 * 4);
    float*  a2   = (float*)carve((size_t)n * 4);
    float*  d2   = (float*)carve((size_t)n * 4);
    float*  ps   = (float*)carve((size_t)n * 4);
    float*  pd   = (float*)carve((size_t)n * 4);
    int*    offs = (int*)carve((size_t)n * 4);
    int*    oendp= (int*)carve((size_t)n * 4);
    int*    bcur = (int*)carve(512 * 4);
    int*    ssrc = (int*)carve((size_t)nbuck * CAP2 * 4);
    unsigned* brec = (unsigned*)carve((size_t)nbuck * CAP2 * 4);

    float* outp = (float*)d_out;

    const int gbin  = (ep + 4095) / 4096;     // 416
    const int gmlp  = (e + 255) / 256;        // 6250
    const int gnode1 = (n + 3) / 4;           // 25000
    const int npair = (n + 1) / 2;            // 50000 waves

    // 1) init cursors
    k_binit3<<<2, 256, 0, stream>>>(bcur, nbuck);
    // 2) FAT: bin || edge MLP (independent; overlap)
    k_binF<<<gbin + gmlp, 256, 0, stream>>>(src, dst, bcur, brec, eattr,
                                            mlp_W1, mlp_b1, mlp_W2, mlp_b2,
                                            fc_W, fc_b, outp, e, ep, nbuck, gbin);
    // 3) FAT: fine sort || node1 (independent; overlap)
    k_fineF<<<nbuck + gnode1, 256, 0, stream>>>(brec, bcur, offs, oendp, ssrc,
                                                x, W1, att_s1, att_d1,
                                                h1h, a1, d1, n, nbuck);
    // 4) conv1 aggregate + folded conv2 node transform
    k_agg1F<<<(npair * 64 + 255) / 256, 256, 0, stream>>>(
        h1h, a1, d1, b1, W2, att_s2, att_d2, offs, oendp, ssrc, h2h, a2, d2, n);
    // 5) conv2 aggregate -> ps/pd
    k_agg2<<<(npair * 64 + 255) / 256, 256, 0, stream>>>(
        h2h, a2, d2, b2, fc_W, offs, oendp, ssrc, ps, pd, n);
    // 6) final add
    k_final2<<<(e + 255) / 256, 256, 0, stream>>>(src, dst, ps, pd, outp, e);
}

// Round 16
// 183.676 us; speedup vs baseline: 1.3043x; 1.0132x over previous
//
#include <hip/hip_runtime.h>
#include <hip/hip_bf16.h>
#include <hip/hip_fp16.h>

// EdgeGAT: 2-layer GAT (heads=4x16 then 1x16) + edge MLP + fc scoring.
// Fixed sizes: N=100000, E=1600000, F_IN=32, EF=8, HID=16.
// Strategy:
//  - CSR by dst via one-pass slack-bucket binning.
//  - Fat kernels: {bin || edge-MLP}, {fine-sort || node1}. (Round 14: fusing
//    MLP into the gather kernel collapses occupancy via branch-union VGPRs.)
//  - k_agg1F: FOUR nodes per wave (independent 16-lane quarters) — r15 showed
//    the kernel is latency-bound (VALU 55%, HBM 25%); quadrupling chains per
//    wave at equal traffic is the remaining lever. Epilogue matvec remapped
//    lane=channel with broadcast-only LDS reads (sO quarter stride 68).
//  - conv2's node transform folded into k_agg1's epilogue.
//  - ELU via __expf(x)-1; h1/h2 fp16; fp32 accumulation everywhere.
//  - Skip segment_max (softmax shift-invariant; scores are O(1)).
//  - fc epilogue folded into per-node ps/pd; final kernel is a thin
//    out[e] += ps[src]+pd[dst].

#define FIN 32
#define C1 64   // 4 heads * 16
#define HID 16
#define BSH 8          // 256 nodes per bucket
#define CAP2 6144      // slack bucket capacity (mean 4352, sigma ~64)
#define SOP 68         // padded sO quarter stride (dwords): 68%32=4 -> quarters split banks

__device__ __forceinline__ float leaky02(float x) {
    return x > 0.f ? x : 0.2f * x;
}

// ---------------- init: bucket cursors at slack bases ----------------
__global__ void k_binit3(int* __restrict__ bcur, int nbuck) {
    int b = blockIdx.x * blockDim.x + threadIdx.x;
    if (b < nbuck) bcur[b] = b * CAP2;
}

// ---------------- FAT 1: bucket binning  ||  edge MLP ----------------
__global__ void __launch_bounds__(256) k_binF(
        const int* __restrict__ src, const int* __restrict__ dst,
        int* __restrict__ bcur, unsigned* __restrict__ brec,
        const float* __restrict__ ea,
        const float* __restrict__ mlpW1, const float* __restrict__ mlpb1,
        const float* __restrict__ mlpW2, const float* __restrict__ mlpb2,
        const float* __restrict__ fcW, const float* __restrict__ fcb,
        float* __restrict__ outp,
        int e, int ep, int nbuck, int gbin) {
    __shared__ int cnt[512];
    __shared__ int cur[512];
    __shared__ float sW[128];
    __shared__ float sb[16];
    __shared__ float sw2[17];
    int tid = threadIdx.x;
    if ((int)blockIdx.x < gbin) {
        int cb = blockIdx.x * 4096;
        for (int j = tid; j < 512; j += 256) cnt[j] = 0;
        __syncthreads();
        unsigned rec[16];
        int bk[16];
#pragma unroll
        for (int t = 0; t < 16; t++) {
            int i = cb + t * 256 + tid;
            bk[t] = -1;
            if (i < ep) {
                int s, d;
                if (i < e) { s = src[i]; d = dst[i]; }
                else       { s = i - e; d = s; }
                int b = d >> BSH;
                rec[t] = ((unsigned)(d & 255) << 17) | (unsigned)s;
                bk[t] = b;
                atomicAdd(&cnt[b], 1);
            }
        }
        __syncthreads();
        for (int b = tid; b < nbuck; b += 256) {
            int c = cnt[b];
            cur[b] = (c > 0) ? atomicAdd(&bcur[b], c) : 0;
        }
        __syncthreads();
#pragma unroll
        for (int t = 0; t < 16; t++) {
            if (bk[t] >= 0) {
                int p = atomicAdd(&cur[bk[t]], 1);
                if (p < (bk[t] + 1) * CAP2)   // slack-overflow guard
                    brec[p] = rec[t];
            }
        }
    } else {
        if (tid < 128) sW[tid] = mlpW1[tid];
        if (tid < 16)  sb[tid] = mlpb1[tid];
        if (tid < 16) {
            float s = 0.f;
#pragma unroll
            for (int k = 0; k < 16; k++) s += mlpW2[tid * 16 + k] * fcW[32 + k];
            sw2[tid] = s;
        } else if (tid == 16) {
            float s = fcb[0];
            for (int k = 0; k < 16; k++) s += mlpb2[k] * fcW[32 + k];
            sw2[16] = s;
        }
        __syncthreads();
        int eid = ((int)blockIdx.x - gbin) * 256 + tid;
        if (eid >= e) return;
        const float4* ev = (const float4*)ea + (size_t)eid * 4;
        float4 v0 = ev[0], v1 = ev[1], v2 = ev[2], v3 = ev[3];
        float ef[8] = { v0.x * v2.x, v0.y * v2.y, v0.z * v2.z, v0.w * v2.w,
                        v1.x * v3.x, v1.y * v3.y, v1.z * v3.z, v1.w * v3.w };
        float acc = sw2[16];
#pragma unroll
        for (int j = 0; j < 16; j++) {
            float tt = sb[j];
#pragma unroll
            for (int i = 0; i < 8; i++) tt += ef[i] * sW[i * 16 + j];
            acc += fmaxf(tt, 0.f) * sw2[j];
        }
        outp[eid] = acc;
    }
}

// ---------------- FAT 2: per-bucket fine sort  ||  node1 ----------------
__global__ void __launch_bounds__(256) k_fineF(
        const unsigned* __restrict__ brec, const int* __restrict__ bcur,
        int* __restrict__ offs, int* __restrict__ oend, int* __restrict__ ssrc,
        const float* __restrict__ x, const float* __restrict__ W1,
        const float* __restrict__ att_s, const float* __restrict__ att_d,
        __half* __restrict__ h1h, float* __restrict__ a1, float* __restrict__ d1,
        int n, int gfine) {
    __shared__ int lcnt[256];
    __shared__ int sbuf[256];
    __shared__ float sW[FIN * C1];     // 8 KB (node1 path)
    __shared__ float sA[C1], sD[C1];
    __shared__ float sX[4 * FIN];
    int tid = threadIdx.x;
    if ((int)blockIdx.x < gfine) {
        int b = blockIdx.x;
        int n0 = b << BSH;
        int base = b * CAP2;
        int cnt = min(bcur[b] - base, CAP2);
        lcnt[tid] = 0;
        __syncthreads();
        for (int i = tid; i < cnt; i += 256) {
            unsigned r = brec[base + i];
            atomicAdd(&lcnt[r >> 17], 1);
        }
        __syncthreads();
        int v = lcnt[tid];
        sbuf[tid] = v;
        __syncthreads();
        for (int off = 1; off < 256; off <<= 1) {
            int u = (tid >= off) ? sbuf[tid - off] : 0;
            __syncthreads();
            sbuf[tid] += u;
            __syncthreads();
        }
        int excl = sbuf[tid] - v;
        if (n0 + tid < n) {
            offs[n0 + tid] = base + excl;
            oend[n0 + tid] = base + excl + v;
        }
        lcnt[tid] = base + excl;    // absolute cursor
        __syncthreads();
        for (int i = tid; i < cnt; i += 256) {
            unsigned r = brec[base + i];
            int p = atomicAdd(&lcnt[r >> 17], 1);
            ssrc[p] = (int)(r & 0x1FFFF);   // 24KB window, L2-absorbed
        }
    } else {
        int nb = (int)blockIdx.x - gfine;   // 4 nodes per block
        for (int i = tid; i < FIN * C1; i += 256) sW[i] = W1[i];
        if (tid < C1) { sA[tid] = att_s[tid]; sD[tid] = att_d[tid]; }
        int bse = nb * 4;
        if (tid < 4 * FIN) {
            int nn = bse + (tid >> 5);
            sX[tid] = (nn < n) ? x[(size_t)nn * FIN + (tid & 31)] : 0.f;
        }
        __syncthreads();
        int li = tid >> 6, c = tid & 63;
        int node = bse + li;
        if (node >= n) return;
        const float* xr = sX + li * FIN;
        float acc = 0.f;
#pragma unroll
        for (int k = 0; k < FIN; k++) acc += xr[k] * sW[k * C1 + c];
        h1h[(size_t)node * C1 + c] = __float2half(acc);
        float pa = acc * sA[c], pb = acc * sD[c];
#pragma unroll
        for (int m = 8; m >= 1; m >>= 1) {
            pa += __shfl_xor(pa, m, 16);
            pb += __shfl_xor(pb, m, 16);
        }
        if ((c & 15) == 0) {
            a1[node * 4 + (c >> 4)] = pa;
            d1[node * 4 + (c >> 4)] = pb;
        }
    }
}

// ---------------- conv1 aggregate + ELU + folded conv2 node transform -----
// FOUR nodes per wave (independent 16-lane quarters). Per quarter: chunk of
// 16 edges; 2 edge-groups x 8 lanes gather 128B fp16 rows (unroll 4).
// Epilogue: single shfl(8) reduce; sO staged per-quarter (stride 68 -> banks
// split); matvec lane=channel c, k=0..63 with broadcast LDS reads.
__global__ void __launch_bounds__(256) k_agg1F(
        const __half* __restrict__ h1h, const float* __restrict__ a1,
        const float* __restrict__ d1, const float* __restrict__ b1,
        const float* __restrict__ W2,
        const float* __restrict__ att_s2, const float* __restrict__ att_d2,
        const int* __restrict__ offs, const int* __restrict__ oend,
        const int* __restrict__ ssrc,
        __half* __restrict__ h2h, float* __restrict__ a2, float* __restrict__ d2,
        int n) {
    __shared__ float4 w4l[4][64];
    __shared__ int    sil[4][64];
    __shared__ float  sO[4][4][SOP];
    __shared__ float  sW2[C1 * HID];   // 4 KB row-major
    int tid = threadIdx.x;
    for (int i = tid; i < C1 * HID; i += 256) sW2[i] = W2[i];
    __syncthreads();
    int wid = (int)((blockIdx.x * (size_t)blockDim.x + tid) >> 6);
    int lane = tid & 63;
    int wl = tid >> 6;
    int quarter = lane >> 4;      // 0..3
    int lane16 = lane & 15;
    int node = wid * 4 + quarter;
    if (node >= n) return;
    int sub = lane16 & 7;         // 16B granule within 128B row
    int g   = lane16 >> 3;        // edge group 0..1
    int head = sub >> 1;
    unsigned lane_off = (unsigned)sub * 16u;
    const char* hb = (const char*)h1h;
    float4 dv = ((const float4*)d1)[node];
    int s0 = offs[node], s1v = oend[node];
    float acc[8] = {0.f, 0.f, 0.f, 0.f, 0.f, 0.f, 0.f, 0.f};
    float dsum = 0.f;
    for (int base = s0; base < s1v; base += 16) {
        int cnt = min(16, s1v - base);
        int sl = (lane16 < cnt) ? ssrc[base + lane16] : 0;
        float4 a4 = ((const float4*)a1)[(unsigned)sl];
        float4 w4;
        if (lane16 < cnt) {
            w4.x = __expf(leaky02(a4.x + dv.x));
            w4.y = __expf(leaky02(a4.y + dv.y));
            w4.z = __expf(leaky02(a4.z + dv.z));
            w4.w = __expf(leaky02(a4.w + dv.w));
        } else {
            w4.x = w4.y = w4.z = w4.w = 0.f;
        }
        w4l[wl][lane] = w4;
        sil[wl][lane] = sl << 7;           // pre-shifted byte offset
        __builtin_amdgcn_wave_barrier();
        int cnt2 = (cnt + 1) & ~1;
        int lbase = quarter << 4;
#pragma unroll 4
        for (int j = g; j < cnt2; j += 2) {
            int soff = sil[wl][lbase + j];
            float w = ((const float*)&w4l[wl][lbase + j])[head];
            float4 raw = *(const float4*)(hb + (unsigned)soff + lane_off);
            const __half* hr = (const __half*)&raw;
            acc[0] = fmaf(__half2float(hr[0]), w, acc[0]);
            acc[1] = fmaf(__half2float(hr[1]), w, acc[1]);
            acc[2] = fmaf(__half2float(hr[2]), w, acc[2]);
            acc[3] = fmaf(__half2float(hr[3]), w, acc[3]);
            acc[4] = fmaf(__half2float(hr[4]), w, acc[4]);
            acc[5] = fmaf(__half2float(hr[5]), w, acc[5]);
            acc[6] = fmaf(__half2float(hr[6]), w, acc[6]);
            acc[7] = fmaf(__half2float(hr[7]), w, acc[7]);
            dsum += w;
        }
        __builtin_amdgcn_wave_barrier();
    }
    // combine the 2 edge groups (lane bit 3) — stays within the quarter
#pragma unroll
    for (int i = 0; i < 8; i++) acc[i] += __shfl_xor(acc[i], 8, 64);
    dsum += __shfl_xor(dsum, 8, 64);
    if (lane16 < 8) {    // sub-lane owns 8 channels: bias + ELU, stage to sO
        float inv = 1.f / (dsum + 1e-16f);
        float4 bA = ((const float4*)b1)[lane16 * 2];
        float4 bB = ((const float4*)b1)[lane16 * 2 + 1];
        float4 oA, oB;
        oA.x = acc[0] * inv + bA.x;
        oA.y = acc[1] * inv + bA.y;
        oA.z = acc[2] * inv + bA.z;
        oA.w = acc[3] * inv + bA.w;
        oB.x = acc[4] * inv + bB.x;
        oB.y = acc[5] * inv + bB.y;
        oB.z = acc[6] * inv + bB.z;
        oB.w = acc[7] * inv + bB.w;
        oA.x = oA.x > 0.f ? oA.x : (__expf(oA.x) - 1.f);
        oA.y = oA.y > 0.f ? oA.y : (__expf(oA.y) - 1.f);
        oA.z = oA.z > 0.f ? oA.z : (__expf(oA.z) - 1.f);
        oA.w = oA.w > 0.f ? oA.w : (__expf(oA.w) - 1.f);
        oB.x = oB.x > 0.f ? oB.x : (__expf(oB.x) - 1.f);
        oB.y = oB.y > 0.f ? oB.y : (__expf(oB.y) - 1.f);
        oB.z = oB.z > 0.f ? oB.z : (__expf(oB.z) - 1.f);
        oB.w = oB.w > 0.f ? oB.w : (__expf(oB.w) - 1.f);
        *((float4*)&sO[wl][quarter][lane16 * 8])     = oA;
        *((float4*)&sO[wl][quarter][lane16 * 8 + 4]) = oB;
    }
    __builtin_amdgcn_wave_barrier();
    // folded conv2 node transform: lane16 = channel c; k=0..63.
    // sW2 reads: same addr across quarters (broadcast); sO reads: 4 distinct
    // banks (stride 68). Conflict-free.
    int c = lane16;
    const float* orow = sO[wl][quarter];
    float part = 0.f;
#pragma unroll
    for (int k = 0; k < C1; k++)
        part = fmaf(orow[k], sW2[k * HID + c], part);
    h2h[(size_t)node * HID + c] = __float2half(part);
    float pa = part * att_s2[c], pb = part * att_d2[c];
#pragma unroll
    for (int m = 8; m >= 1; m >>= 1) {
        pa += __shfl_xor(pa, m, 64);
        pb += __shfl_xor(pb, m, 64);
    }
    if (lane16 == 0) { a2[node] = pa; d2[node] = pb; }
}

// ---------------- conv2 aggregate + bias + fold fc -> ps/pd ----------------
// TWO nodes per wave; per half: 16 groups x 2 lanes gather 32B fp16 rows.
__global__ void __launch_bounds__(256) k_agg2(
        const __half* __restrict__ h2h, const float* __restrict__ a2,
        const float* __restrict__ d2, const float* __restrict__ b2,
        const float* __restrict__ fcW,
        const int* __restrict__ offs, const int* __restrict__ oend,
        const int* __restrict__ ssrc,
        float* __restrict__ ps, float* __restrict__ pd, int n) {
    __shared__ float2 wsl[4][64];
    int wid = (int)((blockIdx.x * (size_t)blockDim.x + threadIdx.x) >> 6);
    int lane = threadIdx.x & 63;
    int wl = threadIdx.x >> 6;
    int which = lane >> 5;
    int lane32 = lane & 31;
    int node = wid * 2 + which;
    if (node >= n) return;
    int sub = lane32 & 1;
    int g   = lane32 >> 1;
    unsigned lane_off = (unsigned)sub * 16u;
    const char* hb = (const char*)h2h;
    float dvv = d2[node];
    int s0 = offs[node], s1v = oend[node];
    float acc[8] = {0.f, 0.f, 0.f, 0.f, 0.f, 0.f, 0.f, 0.f};
    float dsum = 0.f;
    for (int base = s0; base < s1v; base += 32) {
        int cnt = min(32, s1v - base);
        int sl = (lane32 < cnt) ? ssrc[base + lane32] : 0;
        float av = a2[(unsigned)sl];
        float w = (lane32 < cnt) ? __expf(leaky02(av + dvv)) : 0.f;
        wsl[wl][lane] = make_float2(w, __int_as_float(sl << 5));  // pre-shifted
        __builtin_amdgcn_wave_barrier();
        int cnt16 = (cnt + 15) & ~15;
        int lbase = which << 5;
#pragma unroll 2
        for (int j = g; j < cnt16; j += 16) {
            float2 e0 = wsl[wl][lbase + j];
            unsigned soff = (unsigned)__float_as_int(e0.y);
            float4 raw = *(const float4*)(hb + soff + lane_off);
            const __half* hr = (const __half*)&raw;
            acc[0] = fmaf(__half2float(hr[0]), e0.x, acc[0]);
            acc[1] = fmaf(__half2float(hr[1]), e0.x, acc[1]);
            acc[2] = fmaf(__half2float(hr[2]), e0.x, acc[2]);
            acc[3] = fmaf(__half2float(hr[3]), e0.x, acc[3]);
            acc[4] = fmaf(__half2float(hr[4]), e0.x, acc[4]);
            acc[5] = fmaf(__half2float(hr[5]), e0.x, acc[5]);
            acc[6] = fmaf(__half2float(hr[6]), e0.x, acc[6]);
            acc[7] = fmaf(__half2float(hr[7]), e0.x, acc[7]);
            dsum += e0.x;
        }
        __builtin_amdgcn_wave_barrier();
    }
#pragma unroll
    for (int m = 2; m <= 16; m <<= 1) {
#pragma unroll
        for (int i = 0; i < 8; i++) acc[i] += __shfl_xor(acc[i], m, 64);
        dsum += __shfl_xor(dsum, m, 64);
    }
    float p1 = 0.f, p2 = 0.f;
    if (lane32 < 2) {
        float inv = 1.f / (dsum + 1e-16f);
        float4 bA = ((const float4*)b2)[lane32 * 2];
        float4 bB = ((const float4*)b2)[lane32 * 2 + 1];
        float4 fsA = ((const float4*)fcW)[lane32 * 2];
        float4 fsB = ((const float4*)fcW)[lane32 * 2 + 1];
        float4 fdA = ((const float4*)fcW)[4 + lane32 * 2];
        float4 fdB = ((const float4*)fcW)[4 + lane32 * 2 + 1];
        float h0 = acc[0] * inv + bA.x, h1v = acc[1] * inv + bA.y;
        float h2v = acc[2] * inv + bA.z, h3 = acc[3] * inv + bA.w;
        float h4 = acc[4] * inv + bB.x, h5 = acc[5] * inv + bB.y;
        float h6 = acc[6] * inv + bB.z, h7 = acc[7] * inv + bB.w;
        p1 = h0 * fsA.x + h1v * fsA.y + h2v * fsA.z + h3 * fsA.w
           + h4 * fsB.x + h5 * fsB.y + h6 * fsB.z + h7 * fsB.w;
        p2 = h0 * fdA.x + h1v * fdA.y + h2v * fdA.z + h3 * fdA.w
           + h4 * fdB.x + h5 * fdB.y + h6 * fdB.z + h7 * fdB.w;
    }
    p1 += __shfl_xor(p1, 1, 64);
    p2 += __shfl_xor(p2, 1, 64);
    if (lane32 == 0) { ps[node] = p1; pd[node] = p2; }
}

// ---------------- final: add per-node scalars to edge-MLP partial ----------
__global__ void __launch_bounds__(256) k_final2(
        const int* __restrict__ src, const int* __restrict__ dst,
        const float* __restrict__ ps, const float* __restrict__ pd,
        float* __restrict__ out, int e) {
    int eid = blockIdx.x * blockDim.x + threadIdx.x;
    if (eid < e) out[eid] += ps[src[eid]] + pd[dst[eid]];
}

extern "C" void kernel_launch(void* const* d_in, const int* in_sizes, int n_in,
                              void* d_out, int out_size, void* d_ws, size_t ws_size,
                              hipStream_t stream) {
    const float* x        = (const float*)d_in[0];
    const int*   eidx     = (const int*)d_in[1];
    const float* eattr    = (const float*)d_in[2];
    const float* W1       = (const float*)d_in[5];
    const float* att_s1   = (const float*)d_in[6];
    const float* att_d1   = (const float*)d_in[7];
    const float* b1       = (const float*)d_in[8];
    const float* W2       = (const float*)d_in[9];
    const float* att_s2   = (const float*)d_in[10];
    const float* att_d2   = (const float*)d_in[11];
    const float* b2       = (const float*)d_in[12];
    const float* mlp_W1   = (const float*)d_in[13];
    const float* mlp_b1   = (const float*)d_in[14];
    const float* mlp_W2   = (const float*)d_in[15];
    const float* mlp_b2   = (const float*)d_in[16];
    const float* fc_W     = (const float*)d_in[17];
    const float* fc_b     = (const float*)d_in[18];

    const int n = in_sizes[0] / FIN;          // 100000
    const int e = in_sizes[2] / 16;           // 1600000
    const int ep = e + n;                     // with self loops
    const int* src = eidx;
    const int* dst = eidx + e;
    const int nbuck = (n + 255) >> BSH;       // 391 (<= 512)

    // workspace layout (byte-carved, 256B-aligned blocks)
    char* p = (char*)d_ws;
    auto carve = [&](size_t bytes) {
        char* r = p;
        p += (bytes + 255) & ~(size_t)255;
        return r;
    };
    __half* h1h  = (__half*)carve((size_t)n * C1 * 2);
    __half* h2h  = (__half*)carve((size_t)n * HID * 2);
    float*  a1   = (float*)carve((size_t)n * 4 * 4);
    float*  d1   = (float*)carve((size_t)n * 4 * 4);
    float*  a2   = (float*)carve((size_t)n * 4);
    float*  d2   = (float*)carve((size_t)n * 4);
    float*  ps   = (float*)carve((size_t)n * 4);
    float*  pd   = (float*)carve((size_t)n * 4);
    int*    offs = (int*)carve((size_t)n * 4);
    int*    oendp= (int*)carve((size_t)n * 4);
    int*    bcur = (int*)carve(512 * 4);
    int*    ssrc = (int*)carve((size_t)nbuck * CAP2 * 4);
    unsigned* brec = (unsigned*)carve((size_t)nbuck * CAP2 * 4);

    float* outp = (float*)d_out;

    const int gbin  = (ep + 4095) / 4096;     // 416
    const int gmlp  = (e + 255) / 256;        // 6250
    const int gnode1 = (n + 3) / 4;           // 25000
    const int nquad = (n + 3) / 4;            // 25000 waves (4 nodes each)
    const int npair = (n + 1) / 2;            // 50000 waves (k_agg2)

    // 1) init cursors
    k_binit3<<<2, 256, 0, stream>>>(bcur, nbuck);
    // 2) FAT: bin || edge MLP (independent; overlap)
    k_binF<<<gbin + gmlp, 256, 0, stream>>>(src, dst, bcur, brec, eattr,
                                            mlp_W1, mlp_b1, mlp_W2, mlp_b2,
                                            fc_W, fc_b, outp, e, ep, nbuck, gbin);
    // 3) FAT: fine sort || node1 (independent; overlap)
    k_fineF<<<nbuck + gnode1, 256, 0, stream>>>(brec, bcur, offs, oendp, ssrc,
                                                x, W1, att_s1, att_d1,
                                                h1h, a1, d1, n, nbuck);
    // 4) conv1 aggregate + folded conv2 node transform (4 nodes/wave)
    k_agg1F<<<(nquad * 64 + 255) / 256, 256, 0, stream>>>(
        h1h, a1, d1, b1, W2, att_s2, att_d2, offs, oendp, ssrc, h2h, a2, d2, n);
    // 5) conv2 aggregate -> ps/pd
    k_agg2<<<(npair * 64 + 255) / 256, 256, 0, stream>>>(
        h2h, a2, d2, b2, fc_W, offs, oendp, ssrc, ps, pd, n);
    // 6) final add
    k_final2<<<(e + 255) / 256, 256, 0, stream>>>(src, dst, ps, pd, outp, e);
}

// Round 17
// 179.347 us; speedup vs baseline: 1.3358x; 1.0241x over previous
//
#include <hip/hip_runtime.h>
#include <hip/hip_bf16.h>
#include <hip/hip_fp16.h>

// EdgeGAT: 2-layer GAT (heads=4x16 then 1x16) + edge MLP + fc scoring.
// Fixed sizes: N=100000, E=1600000, F_IN=32, EF=8, HID=16.
// Strategy:
//  - CSR by dst via one-pass slack-bucket binning.
//  - Fat kernels: {bin || edge-MLP}, {fine-sort || node1}.
//  - k_agg1F AND k_agg2: FOUR nodes per wave (independent 16-lane quarters)
//    — both aggregates are latency-bound; 4x chains per wave at equal
//    traffic. agg1F epilogue: folded conv2 transform, lane=channel matvec
//    with broadcast LDS reads (sO quarter stride 68).
//  - ELU via __expf(x)-1; h1/h2 fp16; fp32 accumulation everywhere.
//  - Skip segment_max (softmax shift-invariant; scores are O(1)).
//  - fc epilogue folded into per-node ps/pd; final kernel is a thin
//    out[e] += ps[src]+pd[dst].

#define FIN 32
#define C1 64   // 4 heads * 16
#define HID 16
#define BSH 8          // 256 nodes per bucket
#define CAP2 6144      // slack bucket capacity (mean 4352, sigma ~64)
#define SOP 68         // padded sO quarter stride (dwords)

__device__ __forceinline__ float leaky02(float x) {
    return x > 0.f ? x : 0.2f * x;
}

// ---------------- init: bucket cursors at slack bases ----------------
__global__ void k_binit3(int* __restrict__ bcur, int nbuck) {
    int b = blockIdx.x * blockDim.x + threadIdx.x;
    if (b < nbuck) bcur[b] = b * CAP2;
}

// ---------------- FAT 1: bucket binning  ||  edge MLP ----------------
__global__ void __launch_bounds__(256) k_binF(
        const int* __restrict__ src, const int* __restrict__ dst,
        int* __restrict__ bcur, unsigned* __restrict__ brec,
        const float* __restrict__ ea,
        const float* __restrict__ mlpW1, const float* __restrict__ mlpb1,
        const float* __restrict__ mlpW2, const float* __restrict__ mlpb2,
        const float* __restrict__ fcW, const float* __restrict__ fcb,
        float* __restrict__ outp,
        int e, int ep, int nbuck, int gbin) {
    __shared__ int cnt[512];
    __shared__ int cur[512];
    __shared__ float sW[128];
    __shared__ float sb[16];
    __shared__ float sw2[17];
    int tid = threadIdx.x;
    if ((int)blockIdx.x < gbin) {
        int cb = blockIdx.x * 4096;
        for (int j = tid; j < 512; j += 256) cnt[j] = 0;
        __syncthreads();
        unsigned rec[16];
        int bk[16];
#pragma unroll
        for (int t = 0; t < 16; t++) {
            int i = cb + t * 256 + tid;
            bk[t] = -1;
            if (i < ep) {
                int s, d;
                if (i < e) { s = src[i]; d = dst[i]; }
                else       { s = i - e; d = s; }
                int b = d >> BSH;
                rec[t] = ((unsigned)(d & 255) << 17) | (unsigned)s;
                bk[t] = b;
                atomicAdd(&cnt[b], 1);
            }
        }
        __syncthreads();
        for (int b = tid; b < nbuck; b += 256) {
            int c = cnt[b];
            cur[b] = (c > 0) ? atomicAdd(&bcur[b], c) : 0;
        }
        __syncthreads();
#pragma unroll
        for (int t = 0; t < 16; t++) {
            if (bk[t] >= 0) {
                int p = atomicAdd(&cur[bk[t]], 1);
                if (p < (bk[t] + 1) * CAP2)   // slack-overflow guard
                    brec[p] = rec[t];
            }
        }
    } else {
        if (tid < 128) sW[tid] = mlpW1[tid];
        if (tid < 16)  sb[tid] = mlpb1[tid];
        if (tid < 16) {
            float s = 0.f;
#pragma unroll
            for (int k = 0; k < 16; k++) s += mlpW2[tid * 16 + k] * fcW[32 + k];
            sw2[tid] = s;
        } else if (tid == 16) {
            float s = fcb[0];
            for (int k = 0; k < 16; k++) s += mlpb2[k] * fcW[32 + k];
            sw2[16] = s;
        }
        __syncthreads();
        int eid = ((int)blockIdx.x - gbin) * 256 + tid;
        if (eid >= e) return;
        const float4* ev = (const float4*)ea + (size_t)eid * 4;
        float4 v0 = ev[0], v1 = ev[1], v2 = ev[2], v3 = ev[3];
        float ef[8] = { v0.x * v2.x, v0.y * v2.y, v0.z * v2.z, v0.w * v2.w,
                        v1.x * v3.x, v1.y * v3.y, v1.z * v3.z, v1.w * v3.w };
        float acc = sw2[16];
#pragma unroll
        for (int j = 0; j < 16; j++) {
            float tt = sb[j];
#pragma unroll
            for (int i = 0; i < 8; i++) tt += ef[i] * sW[i * 16 + j];
            acc += fmaxf(tt, 0.f) * sw2[j];
        }
        outp[eid] = acc;
    }
}

// ---------------- FAT 2: per-bucket fine sort  ||  node1 ----------------
__global__ void __launch_bounds__(256) k_fineF(
        const unsigned* __restrict__ brec, const int* __restrict__ bcur,
        int* __restrict__ offs, int* __restrict__ oend, int* __restrict__ ssrc,
        const float* __restrict__ x, const float* __restrict__ W1,
        const float* __restrict__ att_s, const float* __restrict__ att_d,
        __half* __restrict__ h1h, float* __restrict__ a1, float* __restrict__ d1,
        int n, int gfine) {
    __shared__ int lcnt[256];
    __shared__ int sbuf[256];
    __shared__ float sW[FIN * C1];     // 8 KB (node1 path)
    __shared__ float sA[C1], sD[C1];
    __shared__ float sX[4 * FIN];
    int tid = threadIdx.x;
    if ((int)blockIdx.x < gfine) {
        int b = blockIdx.x;
        int n0 = b << BSH;
        int base = b * CAP2;
        int cnt = min(bcur[b] - base, CAP2);
        lcnt[tid] = 0;
        __syncthreads();
        for (int i = tid; i < cnt; i += 256) {
            unsigned r = brec[base + i];
            atomicAdd(&lcnt[r >> 17], 1);
        }
        __syncthreads();
        int v = lcnt[tid];
        sbuf[tid] = v;
        __syncthreads();
        for (int off = 1; off < 256; off <<= 1) {
            int u = (tid >= off) ? sbuf[tid - off] : 0;
            __syncthreads();
            sbuf[tid] += u;
            __syncthreads();
        }
        int excl = sbuf[tid] - v;
        if (n0 + tid < n) {
            offs[n0 + tid] = base + excl;
            oend[n0 + tid] = base + excl + v;
        }
        lcnt[tid] = base + excl;    // absolute cursor
        __syncthreads();
        for (int i = tid; i < cnt; i += 256) {
            unsigned r = brec[base + i];
            int p = atomicAdd(&lcnt[r >> 17], 1);
            ssrc[p] = (int)(r & 0x1FFFF);   // 24KB window, L2-absorbed
        }
    } else {
        int nb = (int)blockIdx.x - gfine;   // 4 nodes per block
        for (int i = tid; i < FIN * C1; i += 256) sW[i] = W1[i];
        if (tid < C1) { sA[tid] = att_s[tid]; sD[tid] = att_d[tid]; }
        int bse = nb * 4;
        if (tid < 4 * FIN) {
            int nn = bse + (tid >> 5);
            sX[tid] = (nn < n) ? x[(size_t)nn * FIN + (tid & 31)] : 0.f;
        }
        __syncthreads();
        int li = tid >> 6, c = tid & 63;
        int node = bse + li;
        if (node >= n) return;
        const float* xr = sX + li * FIN;
        float acc = 0.f;
#pragma unroll
        for (int k = 0; k < FIN; k++) acc += xr[k] * sW[k * C1 + c];
        h1h[(size_t)node * C1 + c] = __float2half(acc);
        float pa = acc * sA[c], pb = acc * sD[c];
#pragma unroll
        for (int m = 8; m >= 1; m >>= 1) {
            pa += __shfl_xor(pa, m, 16);
            pb += __shfl_xor(pb, m, 16);
        }
        if ((c & 15) == 0) {
            a1[node * 4 + (c >> 4)] = pa;
            d1[node * 4 + (c >> 4)] = pb;
        }
    }
}

// ---------------- conv1 aggregate + ELU + folded conv2 node transform -----
// FOUR nodes per wave (16-lane quarters); 2 edge-groups x 8 lanes gather
// 128B fp16 rows (full unroll: 8 loads in flight). Epilogue: shfl(8) reduce,
// padded sO stage, lane=channel matvec (broadcast sW2 reads), h2/a2/d2.
__global__ void __launch_bounds__(256) k_agg1F(
        const __half* __restrict__ h1h, const float* __restrict__ a1,
        const float* __restrict__ d1, const float* __restrict__ b1,
        const float* __restrict__ W2,
        const float* __restrict__ att_s2, const float* __restrict__ att_d2,
        const int* __restrict__ offs, const int* __restrict__ oend,
        const int* __restrict__ ssrc,
        __half* __restrict__ h2h, float* __restrict__ a2, float* __restrict__ d2,
        int n) {
    __shared__ float4 w4l[4][64];
    __shared__ int    sil[4][64];
    __shared__ float  sO[4][4][SOP];
    __shared__ float  sW2[C1 * HID];   // 4 KB row-major
    int tid = threadIdx.x;
    for (int i = tid; i < C1 * HID; i += 256) sW2[i] = W2[i];
    __syncthreads();
    int wid = (int)((blockIdx.x * (size_t)blockDim.x + tid) >> 6);
    int lane = tid & 63;
    int wl = tid >> 6;
    int quarter = lane >> 4;      // 0..3
    int lane16 = lane & 15;
    int node = wid * 4 + quarter;
    if (node >= n) return;
    int sub = lane16 & 7;         // 16B granule within 128B row
    int g   = lane16 >> 3;        // edge group 0..1
    int head = sub >> 1;
    unsigned lane_off = (unsigned)sub * 16u;
    const char* hb = (const char*)h1h;
    float4 dv = ((const float4*)d1)[node];
    int s0 = offs[node], s1v = oend[node];
    float acc[8] = {0.f, 0.f, 0.f, 0.f, 0.f, 0.f, 0.f, 0.f};
    float dsum = 0.f;
    for (int base = s0; base < s1v; base += 16) {
        int cnt = min(16, s1v - base);
        int sl = (lane16 < cnt) ? ssrc[base + lane16] : 0;
        float4 a4 = ((const float4*)a1)[(unsigned)sl];
        float4 w4;
        if (lane16 < cnt) {
            w4.x = __expf(leaky02(a4.x + dv.x));
            w4.y = __expf(leaky02(a4.y + dv.y));
            w4.z = __expf(leaky02(a4.z + dv.z));
            w4.w = __expf(leaky02(a4.w + dv.w));
        } else {
            w4.x = w4.y = w4.z = w4.w = 0.f;
        }
        w4l[wl][lane] = w4;
        sil[wl][lane] = sl << 7;           // pre-shifted byte offset
        __builtin_amdgcn_wave_barrier();
        int cnt2 = (cnt + 1) & ~1;
        int lbase = quarter << 4;
#pragma unroll 8
        for (int j = g; j < cnt2; j += 2) {
            int soff = sil[wl][lbase + j];
            float w = ((const float*)&w4l[wl][lbase + j])[head];
            float4 raw = *(const float4*)(hb + (unsigned)soff + lane_off);
            const __half* hr = (const __half*)&raw;
            acc[0] = fmaf(__half2float(hr[0]), w, acc[0]);
            acc[1] = fmaf(__half2float(hr[1]), w, acc[1]);
            acc[2] = fmaf(__half2float(hr[2]), w, acc[2]);
            acc[3] = fmaf(__half2float(hr[3]), w, acc[3]);
            acc[4] = fmaf(__half2float(hr[4]), w, acc[4]);
            acc[5] = fmaf(__half2float(hr[5]), w, acc[5]);
            acc[6] = fmaf(__half2float(hr[6]), w, acc[6]);
            acc[7] = fmaf(__half2float(hr[7]), w, acc[7]);
            dsum += w;
        }
        __builtin_amdgcn_wave_barrier();
    }
    // combine the 2 edge groups (lane bit 3) — stays within the quarter
#pragma unroll
    for (int i = 0; i < 8; i++) acc[i] += __shfl_xor(acc[i], 8, 64);
    dsum += __shfl_xor(dsum, 8, 64);
    if (lane16 < 8) {    // sub-lane owns 8 channels: bias + ELU, stage to sO
        float inv = 1.f / (dsum + 1e-16f);
        float4 bA = ((const float4*)b1)[lane16 * 2];
        float4 bB = ((const float4*)b1)[lane16 * 2 + 1];
        float4 oA, oB;
        oA.x = acc[0] * inv + bA.x;
        oA.y = acc[1] * inv + bA.y;
        oA.z = acc[2] * inv + bA.z;
        oA.w = acc[3] * inv + bA.w;
        oB.x = acc[4] * inv + bB.x;
        oB.y = acc[5] * inv + bB.y;
        oB.z = acc[6] * inv + bB.z;
        oB.w = acc[7] * inv + bB.w;
        oA.x = oA.x > 0.f ? oA.x : (__expf(oA.x) - 1.f);
        oA.y = oA.y > 0.f ? oA.y : (__expf(oA.y) - 1.f);
        oA.z = oA.z > 0.f ? oA.z : (__expf(oA.z) - 1.f);
        oA.w = oA.w > 0.f ? oA.w : (__expf(oA.w) - 1.f);
        oB.x = oB.x > 0.f ? oB.x : (__expf(oB.x) - 1.f);
        oB.y = oB.y > 0.f ? oB.y : (__expf(oB.y) - 1.f);
        oB.z = oB.z > 0.f ? oB.z : (__expf(oB.z) - 1.f);
        oB.w = oB.w > 0.f ? oB.w : (__expf(oB.w) - 1.f);
        *((float4*)&sO[wl][quarter][lane16 * 8])     = oA;
        *((float4*)&sO[wl][quarter][lane16 * 8 + 4]) = oB;
    }
    __builtin_amdgcn_wave_barrier();
    // folded conv2 node transform: lane16 = channel c; k=0..63.
    int c = lane16;
    const float* orow = sO[wl][quarter];
    float part = 0.f;
#pragma unroll
    for (int k = 0; k < C1; k++)
        part = fmaf(orow[k], sW2[k * HID + c], part);
    h2h[(size_t)node * HID + c] = __float2half(part);
    float pa = part * att_s2[c], pb = part * att_d2[c];
#pragma unroll
    for (int m = 8; m >= 1; m >>= 1) {
        pa += __shfl_xor(pa, m, 64);
        pb += __shfl_xor(pb, m, 64);
    }
    if (lane16 == 0) { a2[node] = pa; d2[node] = pb; }
}

// ---------------- conv2 aggregate + bias + fold fc -> ps/pd ----------------
// FOUR nodes per wave (16-lane quarters); 8 edge-groups x 2 lanes gather
// 32B fp16 rows; chunk=16 edges; reduce over lane bits 1..3 then sub (bit 0).
__global__ void __launch_bounds__(256) k_agg2(
        const __half* __restrict__ h2h, const float* __restrict__ a2,
        const float* __restrict__ d2, const float* __restrict__ b2,
        const float* __restrict__ fcW,
        const int* __restrict__ offs, const int* __restrict__ oend,
        const int* __restrict__ ssrc,
        float* __restrict__ ps, float* __restrict__ pd, int n) {
    __shared__ float2 wsl[4][64];
    int tid = threadIdx.x;
    int wid = (int)((blockIdx.x * (size_t)blockDim.x + tid) >> 6);
    int lane = tid & 63;
    int wl = tid >> 6;
    int quarter = lane >> 4;
    int lane16 = lane & 15;
    int node = wid * 4 + quarter;
    if (node >= n) return;
    int sub = lane16 & 1;         // 16B granule within 32B row (8 channels)
    int g   = lane16 >> 1;        // edge group 0..7
    unsigned lane_off = (unsigned)sub * 16u;
    const char* hb = (const char*)h2h;
    float dvv = d2[node];
    int s0 = offs[node], s1v = oend[node];
    float acc[8] = {0.f, 0.f, 0.f, 0.f, 0.f, 0.f, 0.f, 0.f};
    float dsum = 0.f;
    for (int base = s0; base < s1v; base += 16) {
        int cnt = min(16, s1v - base);
        int sl = (lane16 < cnt) ? ssrc[base + lane16] : 0;
        float av = a2[(unsigned)sl];
        float w = (lane16 < cnt) ? __expf(leaky02(av + dvv)) : 0.f;
        wsl[wl][lane] = make_float2(w, __int_as_float(sl << 5));  // pre-shifted
        __builtin_amdgcn_wave_barrier();
        int cnt8 = (cnt + 7) & ~7;
        int lbase = quarter << 4;
#pragma unroll 2
        for (int j = g; j < cnt8; j += 8) {
            float2 e0 = wsl[wl][lbase + j];
            unsigned soff = (unsigned)__float_as_int(e0.y);
            float4 raw = *(const float4*)(hb + soff + lane_off);
            const __half* hr = (const __half*)&raw;
            acc[0] = fmaf(__half2float(hr[0]), e0.x, acc[0]);
            acc[1] = fmaf(__half2float(hr[1]), e0.x, acc[1]);
            acc[2] = fmaf(__half2float(hr[2]), e0.x, acc[2]);
            acc[3] = fmaf(__half2float(hr[3]), e0.x, acc[3]);
            acc[4] = fmaf(__half2float(hr[4]), e0.x, acc[4]);
            acc[5] = fmaf(__half2float(hr[5]), e0.x, acc[5]);
            acc[6] = fmaf(__half2float(hr[6]), e0.x, acc[6]);
            acc[7] = fmaf(__half2float(hr[7]), e0.x, acc[7]);
            dsum += e0.x;
        }
        __builtin_amdgcn_wave_barrier();
    }
    // reduce across the 8 edge groups (lane bits 1..3) — stays within quarter
#pragma unroll
    for (int m = 2; m <= 8; m <<= 1) {
#pragma unroll
        for (int i = 0; i < 8; i++) acc[i] += __shfl_xor(acc[i], m, 64);
        dsum += __shfl_xor(dsum, m, 64);
    }
    // per-sub 8-channel epilogue: bias + fc dots
    float inv = 1.f / (dsum + 1e-16f);
    float4 bA = ((const float4*)b2)[sub * 2];
    float4 bB = ((const float4*)b2)[sub * 2 + 1];
    float4 fsA = ((const float4*)fcW)[sub * 2];
    float4 fsB = ((const float4*)fcW)[sub * 2 + 1];
    float4 fdA = ((const float4*)fcW)[4 + sub * 2];
    float4 fdB = ((const float4*)fcW)[4 + sub * 2 + 1];
    float h0 = acc[0] * inv + bA.x, h1v = acc[1] * inv + bA.y;
    float h2v = acc[2] * inv + bA.z, h3 = acc[3] * inv + bA.w;
    float h4 = acc[4] * inv + bB.x, h5 = acc[5] * inv + bB.y;
    float h6 = acc[6] * inv + bB.z, h7 = acc[7] * inv + bB.w;
    float p1 = h0 * fsA.x + h1v * fsA.y + h2v * fsA.z + h3 * fsA.w
             + h4 * fsB.x + h5 * fsB.y + h6 * fsB.z + h7 * fsB.w;
    float p2 = h0 * fdA.x + h1v * fdA.y + h2v * fdA.z + h3 * fdA.w
             + h4 * fdB.x + h5 * fdB.y + h6 * fdB.z + h7 * fdB.w;
    p1 += __shfl_xor(p1, 1, 64);   // combine the two subs
    p2 += __shfl_xor(p2, 1, 64);
    if (lane16 == 0) { ps[node] = p1; pd[node] = p2; }
}

// ---------------- final: add per-node scalars to edge-MLP partial ----------
__global__ void __launch_bounds__(256) k_final2(
        const int* __restrict__ src, const int* __restrict__ dst,
        const float* __restrict__ ps, const float* __restrict__ pd,
        float* __restrict__ out, int e) {
    int eid = blockIdx.x * blockDim.x + threadIdx.x;
    if (eid < e) out[eid] += ps[src[eid]] + pd[dst[eid]];
}

extern "C" void kernel_launch(void* const* d_in, const int* in_sizes, int n_in,
                              void* d_out, int out_size, void* d_ws, size_t ws_size,
                              hipStream_t stream) {
    const float* x        = (const float*)d_in[0];
    const int*   eidx     = (const int*)d_in[1];
    const float* eattr    = (const float*)d_in[2];
    const float* W1       = (const float*)d_in[5];
    const float* att_s1   = (const float*)d_in[6];
    const float* att_d1   = (const float*)d_in[7];
    const float* b1       = (const float*)d_in[8];
    const float* W2       = (const float*)d_in[9];
    const float* att_s2   = (const float*)d_in[10];
    const float* att_d2   = (const float*)d_in[11];
    const float* b2       = (const float*)d_in[12];
    const float* mlp_W1   = (const float*)d_in[13];
    const float* mlp_b1   = (const float*)d_in[14];
    const float* mlp_W2   = (const float*)d_in[15];
    const float* mlp_b2   = (const float*)d_in[16];
    const float* fc_W     = (const float*)d_in[17];
    const float* fc_b     = (const float*)d_in[18];

    const int n = in_sizes[0] / FIN;          // 100000
    const int e = in_sizes[2] / 16;           // 1600000
    const int ep = e + n;                     // with self loops
    const int* src = eidx;
    const int* dst = eidx + e;
    const int nbuck = (n + 255) >> BSH;       // 391 (<= 512)

    // workspace layout (byte-carved, 256B-aligned blocks)
    char* p = (char*)d_ws;
    auto carve = [&](size_t bytes) {
        char* r = p;
        p += (bytes + 255) & ~(size_t)255;
        return r;
    };
    __half* h1h  = (__half*)carve((size_t)n * C1 * 2);
    __half* h2h  = (__half*)carve((size_t)n * HID * 2);
    float*  a1   = (float*)carve((size_t)n * 4 * 4);
    float*  d1   = (float*)carve((size_t)n * 4 * 4);
    float*  a2   = (float*)carve((size_t)n * 4);
    float*  d2   = (float*)carve((size_t)n * 4);
    float*  ps   = (float*)carve((size_t)n * 4);
    float*  pd   = (float*)carve((size_t)n * 4);
    int*    offs = (int*)carve((size_t)n * 4);
    int*    oendp= (int*)carve((size_t)n * 4);
    int*    bcur = (int*)carve(512 * 4);
    int*    ssrc = (int*)carve((size_t)nbuck * CAP2 * 4);
    unsigned* brec = (unsigned*)carve((size_t)nbuck * CAP2 * 4);

    float* outp = (float*)d_out;

    const int gbin  = (ep + 4095) / 4096;     // 416
    const int gmlp  = (e + 255) / 256;        // 6250
    const int gnode1 = (n + 3) / 4;           // 25000
    const int nquad = (n + 3) / 4;            // 25000 waves (4 nodes each)

    // 1) init cursors
    k_binit3<<<2, 256, 0, stream>>>(bcur, nbuck);
    // 2) FAT: bin || edge MLP (independent; overlap)
    k_binF<<<gbin + gmlp, 256, 0, stream>>>(src, dst, bcur, brec, eattr,
                                            mlp_W1, mlp_b1, mlp_W2, mlp_b2,
                                            fc_W, fc_b, outp, e, ep, nbuck, gbin);
    // 3) FAT: fine sort || node1 (independent; overlap)
    k_fineF<<<nbuck + gnode1, 256, 0, stream>>>(brec, bcur, offs, oendp, ssrc,
                                                x, W1, att_s1, att_d1,
                                                h1h, a1, d1, n, nbuck);
    // 4) conv1 aggregate + folded conv2 node transform (4 nodes/wave)
    k_agg1F<<<(nquad * 64 + 255) / 256, 256, 0, stream>>>(
        h1h, a1, d1, b1, W2, att_s2, att_d2, offs, oendp, ssrc, h2h, a2, d2, n);
    // 5) conv2 aggregate -> ps/pd (4 nodes/wave)
    k_agg2<<<(nquad * 64 + 255) / 256, 256, 0, stream>>>(
        h2h, a2, d2, b2, fc_W, offs, oendp, ssrc, ps, pd, n);
    // 6) final add
    k_final2<<<(e + 255) / 256, 256, 0, stream>>>(src, dst, ps, pd, outp, e);
}